// Round 2
// baseline (799.524 us; speedup 1.0000x reference)
//
#include <hip/hip_runtime.h>

#define NBATCH 8
#define CH 64
#define HH 256
#define WW 256
#define CK 64          // w-chunk width
#define NCK (WW / CK)  // 4 chunks

// One block per (b, h). 256 threads.
// Thread map for 64x64 tiles: r = tid>>2 (row 0..63), g = tid&3, cols g*16..g*16+15.
__global__ __launch_bounds__(256, 2)
void fused_ca(const float* __restrict__ hid, const float* __restrict__ ctx,
              const float* __restrict__ qdw, const float* __restrict__ qdb,
              const float* __restrict__ qpw, const float* __restrict__ qpb,
              const float* __restrict__ kdw, const float* __restrict__ kdb,
              const float* __restrict__ kpw, const float* __restrict__ kpb,
              const float* __restrict__ vdw, const float* __restrict__ vdb,
              const float* __restrict__ vpw, const float* __restrict__ vpb,
              float* __restrict__ out)
{
    __shared__ float sT[CH][CK + 4];    // depthwise-conv chunk          17408 B
    __shared__ float sA[CH][CK + 4];    // q / v chunk                   17408 B
    __shared__ float sBt[CK][CH + 4];   // k^T chunk ([w][d])            17408 B
    __shared__ float sS[CH][CH + 4];    // scores / probs                17408 B
                                        // total 69632 B -> 2 blocks/CU (139 KB <= 160 KB)

    const int tid = threadIdx.x;
    const int b  = blockIdx.x >> 8;     // / HH
    const int h  = blockIdx.x & 255;    // % HH

    const int r  = tid >> 2;            // row (channel) 0..63
    const int g  = tid & 3;
    const int c0 = g * 16;              // col base

    const float SCALE = 0.35355339059327373f; // 1/sqrt(HEAD_SIZE=8)

    // ---- depthwise 3x3 conv for one 64-wide chunk -> sT ----
    auto dwconv = [&](const float* __restrict__ src, const float* __restrict__ dw,
                      const float* __restrict__ db, int wc) {
        float wgt[9];
        #pragma unroll
        for (int i = 0; i < 9; i++) wgt[i] = dw[r * 9 + i];
        const float bias = db[r];
        const int w0 = wc * CK + c0 - 1;   // global w of first tap needed
        float row[3][18];
        #pragma unroll
        for (int dy = 0; dy < 3; dy++) {
            const int hr = h + dy - 1;
            if (hr < 0 || hr >= HH) {
                #pragma unroll
                for (int j = 0; j < 18; j++) row[dy][j] = 0.f;
            } else {
                const float* p = src + (((size_t)b * CH + r) * HH + hr) * WW;
                #pragma unroll
                for (int j = 0; j < 18; j++) {
                    const int w = w0 + j;
                    row[dy][j] = (w >= 0 && w < WW) ? p[w] : 0.f;
                }
            }
        }
        #pragma unroll
        for (int i = 0; i < 16; i++) {
            float acc = bias;
            #pragma unroll
            for (int dy = 0; dy < 3; dy++)
                #pragma unroll
                for (int dx = 0; dx < 3; dx++)
                    acc += row[dy][i + dx] * wgt[dy * 3 + dx];
            sT[r][c0 + i] = acc;
        }
    };

    // ---- pointwise 1x1 conv: 64x64 GEMM over channels, reads sT ----
    // transposed=false -> sA[o][w] ; transposed=true -> sBt[w][o]
    auto pointwise = [&](const float* __restrict__ pw, const float* __restrict__ pb,
                         bool transposed) {
        float acc[16];
        const float bias = pb[r];
        #pragma unroll
        for (int i = 0; i < 16; i++) acc[i] = bias;
        #pragma unroll 4
        for (int c = 0; c < CH; c++) {
            const float wv = pw[r * CH + c];
            #pragma unroll
            for (int i = 0; i < 16; i++)
                acc[i] += wv * sT[c][c0 + i];
        }
        if (transposed) {
            #pragma unroll
            for (int i = 0; i < 16; i++) sBt[c0 + i][r] = acc[i];
        } else {
            #pragma unroll
            for (int i = 0; i < 16; i++) sA[r][c0 + i] = acc[i];
        }
    };

    // ---- phase 1: scores S[c][d] accumulated in registers across chunks ----
    float sacc[16];
    #pragma unroll
    for (int i = 0; i < 16; i++) sacc[i] = 0.f;

    for (int wc = 0; wc < NCK; wc++) {
        dwconv(hid, qdw, qdb, wc);
        __syncthreads();
        pointwise(qpw, qpb, false);      // q chunk -> sA[c][w]
        __syncthreads();
        dwconv(ctx, kdw, kdb, wc);
        __syncthreads();
        pointwise(kpw, kpb, true);       // k chunk -> sBt[w][d]
        __syncthreads();
        // S[c][d] += sum_w q[c][w] * k[d][w]
        #pragma unroll 4
        for (int w = 0; w < CK; w++) {
            const float qv = sA[r][w];
            #pragma unroll
            for (int i = 0; i < 16; i++)
                sacc[i] += qv * sBt[w][c0 + i];
        }
        __syncthreads();
    }

    #pragma unroll
    for (int i = 0; i < 16; i++) sS[r][c0 + i] = sacc[i] * SCALE;
    __syncthreads();

    // ---- softmax over d (row-wise), one thread per row ----
    if (tid < CH) {
        float m = -1e30f;
        for (int d = 0; d < CH; d++) m = fmaxf(m, sS[tid][d]);
        float s = 0.f;
        for (int d = 0; d < CH; d++) {
            const float e = __expf(sS[tid][d] - m);
            sS[tid][d] = e;
            s += e;
        }
        const float inv = 1.f / s;
        for (int d = 0; d < CH; d++) sS[tid][d] *= inv;
    }
    __syncthreads();

    // ---- phase 2: O = P * V, chunk by chunk ----
    for (int wc = 0; wc < NCK; wc++) {
        dwconv(ctx, vdw, vdb, wc);
        __syncthreads();
        pointwise(vpw, vpb, false);      // v chunk -> sA[d][w]
        __syncthreads();
        float o[16];
        #pragma unroll
        for (int i = 0; i < 16; i++) o[i] = 0.f;
        #pragma unroll 4
        for (int d = 0; d < CH; d++) {
            const float p = sS[r][d];
            #pragma unroll
            for (int i = 0; i < 16; i++)
                o[i] += p * sA[d][c0 + i];
        }
        float* po = out + (((size_t)b * CH + r) * HH + h) * WW + wc * CK + c0;
        #pragma unroll
        for (int i = 0; i < 16; i++) po[i] = o[i];
        __syncthreads();
    }
}

extern "C" void kernel_launch(void* const* d_in, const int* in_sizes, int n_in,
                              void* d_out, int out_size, void* d_ws, size_t ws_size,
                              hipStream_t stream) {
    const float* hid = (const float*)d_in[0];
    const float* ctx = (const float*)d_in[1];
    const float* qdw = (const float*)d_in[2];
    const float* qdb = (const float*)d_in[3];
    const float* qpw = (const float*)d_in[4];
    const float* qpb = (const float*)d_in[5];
    const float* kdw = (const float*)d_in[6];
    const float* kdb = (const float*)d_in[7];
    const float* kpw = (const float*)d_in[8];
    const float* kpb = (const float*)d_in[9];
    const float* vdw = (const float*)d_in[10];
    const float* vdb = (const float*)d_in[11];
    const float* vpw = (const float*)d_in[12];
    const float* vpb = (const float*)d_in[13];
    float* out = (float*)d_out;

    dim3 grid(NBATCH * HH);   // 2048 blocks, one per (b, h)
    dim3 block(256);
    fused_ca<<<grid, block, 0, stream>>>(hid, ctx, qdw, qdb, qpw, qpb,
                                         kdw, kdb, kpw, kpb, vdw, vdb, vpw, vpb,
                                         out);
}